// Round 12
// baseline (777.587 us; speedup 1.0000x reference)
//
#include <hip/hip_runtime.h>

#define N_ROWS 8192
#define DIM 256
#define EPSF 1e-8f

typedef _Float16 f16x8 __attribute__((ext_vector_type(8)));
typedef float f32x4 __attribute__((ext_vector_type(4)));

// ---------------------------------------------------------------------------
// D1: inv_norm (fp32) + fp64 column-sums of x_hat via LDS reduce + one
// f64 atomicAdd per thread (proven r1-r10).  512 blocks x 16 rows.
// ---------------------------------------------------------------------------
__global__ __launch_bounds__(256) void k1_norm(const float* __restrict__ T,
                                               float* __restrict__ inv_norm,
                                               double* __restrict__ s) {
    __shared__ double sacc[4][DIM];
    const int tid = threadIdx.x, bid = blockIdx.x;
    const int lane = tid & 63, wave = tid >> 6;
    double a0 = 0, a1 = 0, a2 = 0, a3 = 0;
#pragma unroll
    for (int r = 0; r < 4; ++r) {
        int row = bid * 16 + wave * 4 + r;
        float4 v = ((const float4*)(T + (size_t)row * DIM))[lane];
        float ss = v.x * v.x + v.y * v.y + v.z * v.z + v.w * v.w;
#pragma unroll
        for (int o = 32; o; o >>= 1) ss += __shfl_down(ss, o);
        ss = __shfl(ss, 0);
        float inv = 1.0f / fmaxf(sqrtf(ss), EPSF);
        if (lane == 0) inv_norm[row] = inv;
        a0 += (double)(v.x * inv);
        a1 += (double)(v.y * inv);
        a2 += (double)(v.z * inv);
        a3 += (double)(v.w * inv);
    }
    sacc[wave][lane * 4 + 0] = a0;
    sacc[wave][lane * 4 + 1] = a1;
    sacc[wave][lane * 4 + 2] = a2;
    sacc[wave][lane * 4 + 3] = a3;
    __syncthreads();
    double t = sacc[0][tid] + sacc[1][tid] + sacc[2][tid] + sacc[3][tid];
    atomicAdd(&s[tid], t);
}

// ---------------------------------------------------------------------------
// D2: all remaining phases, one dispatch.  Block-role split + flag chain.
//   blocks    0..511  gemm    -> ctr[0]   (flag lines 128 B apart)
//   blocks  512..1023 rs      -> ctr[32]
//   blocks 1024..1087 reduceM (waits ctr[0]==512)  -> ctr[64]
//   blocks 1088..1599 k3      (waits ctr[64]==64, ctr[32]==512)
// r11 lesson: polls MUST be agent-scope acquire LOADS, not atomicAdd(p,0) —
// 576 RMW-pollers on one line starved the producers' increments (253us).
// Deadlock-free by co-residency: LDS 20480 B (8/CU), launch_bounds(256,7)
// -> >=7 blk/CU -> capacity 1792 >= 1600; deps point low->high block id.
// ---------------------------------------------------------------------------
__global__ __launch_bounds__(256, 7) void k2_all(
    const float* __restrict__ T, const float* __restrict__ inv_norm,
    const double* __restrict__ s, float* __restrict__ inv_rs,
    float* __restrict__ partials, _Float16* __restrict__ Mt,
    float* __restrict__ out, int* __restrict__ counters)
{
    __shared__ _Float16 As[2][64][40];   // 10240 B (shared by gemm & k3 roles)
    __shared__ _Float16 Bs[2][64][40];   // 10240 B
    const int tid = threadIdx.x, bid = blockIdx.x;
    const int lane = tid & 63, wave = tid >> 6;

    auto wait_ge = [&](int* flag, int target) {
        if (tid == 0)
            while (__hip_atomic_load(flag, __ATOMIC_ACQUIRE,
                                     __HIP_MEMORY_SCOPE_AGENT) < target)
                __builtin_amdgcn_s_sleep(8);
        __syncthreads();
        __threadfence();
    };

    if (bid < 512) {
        // ---- gemm role (r10-verified): g = bid, (kx,dy,z) = (4,4,32)
        const int g = bid;
        const int k0 = (g & 3) * 64;
        const int d0 = ((g >> 2) & 3) * 64;
        const int i0 = (g >> 4) * 256;
        const int wy = wave >> 1, wx = wave & 1;
        const int lm = lane & 15, lg = lane >> 4;
        const int i = tid & 31, c8 = (tid >> 5) * 8;
        f32x4 acc[2][2] = {};
        float4 rA[2], rB[2];
        float rI;

        auto stage = [&](int ic) {
            int gi = i0 + ic + i;
            rI = inv_norm[gi];
            const float* rowp = T + (size_t)gi * DIM;
            rA[0] = *(const float4*)(rowp + k0 + c8);
            rA[1] = *(const float4*)(rowp + k0 + c8 + 4);
            rB[0] = *(const float4*)(rowp + d0 + c8);
            rB[1] = *(const float4*)(rowp + d0 + c8 + 4);
        };
        auto commit = [&](int buf) {
#pragma unroll
            for (int j = 0; j < 2; ++j) {
                float4 a = rA[j], b = rB[j];
                int c = c8 + j * 4;
                As[buf][c + 0][i] = (_Float16)(a.x * rI);
                As[buf][c + 1][i] = (_Float16)(a.y * rI);
                As[buf][c + 2][i] = (_Float16)(a.z * rI);
                As[buf][c + 3][i] = (_Float16)(a.w * rI);
                Bs[buf][c + 0][i] = (_Float16)b.x;
                Bs[buf][c + 1][i] = (_Float16)b.y;
                Bs[buf][c + 2][i] = (_Float16)b.z;
                Bs[buf][c + 3][i] = (_Float16)b.w;
            }
        };
        auto compute = [&](int buf) {
            f16x8 af[2], bf[2];
#pragma unroll
            for (int mt = 0; mt < 2; ++mt)
                af[mt] = *(const f16x8*)&As[buf][wy * 32 + mt * 16 + lm][lg * 8];
#pragma unroll
            for (int nt = 0; nt < 2; ++nt)
                bf[nt] = *(const f16x8*)&Bs[buf][wx * 32 + nt * 16 + lm][lg * 8];
#pragma unroll
            for (int mt = 0; mt < 2; ++mt)
#pragma unroll
                for (int nt = 0; nt < 2; ++nt)
                    acc[mt][nt] = __builtin_amdgcn_mfma_f32_16x16x32_f16(
                        af[mt], bf[nt], acc[mt][nt], 0, 0, 0);
        };

        stage(0);
        commit(0);
        __syncthreads();
        for (int c = 1; c < 8; ++c) {
            stage(c * 32);
            compute((c - 1) & 1);
            commit(c & 1);
            __syncthreads();
        }
        compute(1);

        float* pz = partials + (size_t)(g >> 4) * 65536;
#pragma unroll
        for (int mt = 0; mt < 2; ++mt) {
            int km = k0 + wy * 32 + mt * 16 + lg * 4;
#pragma unroll
            for (int nt = 0; nt < 2; ++nt) {
                int dn = d0 + wx * 32 + nt * 16 + lm;
#pragma unroll
                for (int r = 0; r < 4; ++r)
                    pz[(size_t)(km + r) * 256 + dn] = acc[mt][nt][r];
            }
        }
        __threadfence();
        __syncthreads();
        if (tid == 0) atomicAdd(&counters[0], 1);
        return;
    }

    if (bid < 1024) {
        // ---- rs role: 16 rows/block, 4 fp64 row-dots per wave
        // (precision-critical: rs ~6e-4 possible; fp64 keeps err ~1e-9)
        const int base = (bid - 512) * 16 + wave * 4;
        const double s0 = s[lane * 4 + 0];
        const double s1 = s[lane * 4 + 1];
        const double s2 = s[lane * 4 + 2];
        const double s3 = s[lane * 4 + 3];
#pragma unroll
        for (int r = 0; r < 4; ++r) {
            int row = base + r;
            float4 v = ((const float4*)(T + (size_t)row * DIM))[lane];
            double d = (double)v.x * s0 + (double)v.y * s1 +
                       (double)v.z * s2 + (double)v.w * s3;
#pragma unroll
            for (int o = 32; o; o >>= 1) d += __shfl_down(d, o);
            if (lane == 0)
                inv_rs[row] = (float)(1.0 / (d * (double)inv_norm[row]));
        }
        __threadfence();
        __syncthreads();
        if (tid == 0) atomicAdd(&counters[32], 1);
        return;
    }

    if (bid < 1088) {
        // ---- reduceM role: 64 blocks x 1024 outputs; waits for gemm
        wait_ge(&counters[0], 512);
        const int b = bid - 1024;
#pragma unroll
        for (int q = 0; q < 4; ++q) {
            int g = b * 1024 + q * 256 + tid;
            int k = g >> 8, d = g & 255;
            const float* p = partials + (size_t)k * 256 + d;
            float a0 = 0.f, a1 = 0.f, a2 = 0.f, a3 = 0.f;
#pragma unroll
            for (int z = 0; z < 32; z += 4) {
                a0 += p[(size_t)(z + 0) * 65536];
                a1 += p[(size_t)(z + 1) * 65536];
                a2 += p[(size_t)(z + 2) * 65536];
                a3 += p[(size_t)(z + 3) * 65536];
            }
            Mt[(size_t)d * 256 + k] = (_Float16)((a0 + a1) + (a2 + a3));
        }
        __threadfence();
        __syncthreads();
        if (tid == 0) atomicAdd(&counters[64], 1);
        return;
    }

    // ---- k3 role: 512 blocks, 64x64 tile (r4-verified layout), dbuf LDS.
    {
        wait_ge(&counters[64], 64);
        wait_ge(&counters[32], 512);

        const int t = bid - 1088;
        const int i0 = (t >> 2) * 64;
        const int d0 = (t & 3) * 64;
        const int wy = wave >> 1, wx = wave & 1;
        const int lm = lane & 15, lg = lane >> 4;
        f32x4 acc[2][2] = {};
        float4 rA[2];
        float rI[2];
        f16x8 rB;
        const int db = tid >> 2, k8 = (tid & 3) * 8;

        auto stage = [&](int kc) {
#pragma unroll
            for (int j = 0; j < 2; ++j) {
                int idx = tid + 256 * j;
                int ia = idx >> 3;
                int c4 = (idx & 7) * 4;
                int gi = i0 + ia;
                rI[j] = inv_norm[gi];
                rA[j] = *(const float4*)(T + (size_t)gi * DIM + kc + c4);
            }
            rB = *(const f16x8*)(Mt + (size_t)(d0 + db) * 256 + kc + k8);
        };
        auto commit = [&](int buf) {
#pragma unroll
            for (int j = 0; j < 2; ++j) {
                int idx = tid + 256 * j;
                int ia = idx >> 3;
                int c4 = (idx & 7) * 4;
                float inv = rI[j];
                As[buf][ia][c4 + 0] = (_Float16)(rA[j].x * inv);
                As[buf][ia][c4 + 1] = (_Float16)(rA[j].y * inv);
                As[buf][ia][c4 + 2] = (_Float16)(rA[j].z * inv);
                As[buf][ia][c4 + 3] = (_Float16)(rA[j].w * inv);
            }
            *(f16x8*)&Bs[buf][db][k8] = rB;
        };
        auto compute = [&](int buf) {
            f16x8 af[2], bf[2];
#pragma unroll
            for (int ti = 0; ti < 2; ++ti)
                af[ti] = *(const f16x8*)&As[buf][wy * 32 + ti * 16 + lm][lg * 8];
#pragma unroll
            for (int tj = 0; tj < 2; ++tj)
                bf[tj] = *(const f16x8*)&Bs[buf][wx * 32 + tj * 16 + lm][lg * 8];
#pragma unroll
            for (int ti = 0; ti < 2; ++ti)
#pragma unroll
                for (int tj = 0; tj < 2; ++tj)
                    acc[ti][tj] = __builtin_amdgcn_mfma_f32_16x16x32_f16(
                        af[ti], bf[tj], acc[ti][tj], 0, 0, 0);
        };

        stage(0);
        commit(0);
        __syncthreads();
        for (int c = 1; c < 8; ++c) {
            stage(c * 32);
            compute((c - 1) & 1);
            commit(c & 1);
            __syncthreads();
        }
        compute(1);

#pragma unroll
        for (int ti = 0; ti < 2; ++ti) {
#pragma unroll
            for (int r = 0; r < 4; ++r) {
                int gi = i0 + wy * 32 + ti * 16 + lg * 4 + r;
                float ir = inv_rs[gi];
#pragma unroll
                for (int tj = 0; tj < 2; ++tj)
                    out[(size_t)gi * DIM + d0 + wx * 32 + tj * 16 + lm] =
                        acc[ti][tj][r] * ir;
            }
        }
    }
}

// ---------------------------------------------------------------------------
extern "C" void kernel_launch(void* const* d_in, const int* in_sizes, int n_in,
                              void* d_out, int out_size, void* d_ws, size_t ws_size,
                              hipStream_t stream) {
    const float* T = (const float*)d_in[0];
    float* out = (float*)d_out;

    // workspace layout (16B-aligned, ~8.6 MB of 256 MiB):
    //   [0,       32768)   inv_norm  float[8192]
    //   [32768,   34816)   s         double[256]
    //   [34816,   35840)   counters  int[256]  (flags at [0],[32],[64])
    //   [35840,   68608)   inv_rs    float[8192]
    //   [68608,   199680)  Mt        _Float16[256][256]  (M transposed)
    //   [199680,  +8 MiB)  partials  float[32][256][256]
    char* ws = (char*)d_ws;
    float* inv_norm = (float*)(ws);
    double* s = (double*)(ws + 32768);
    int* counters = (int*)(ws + 34816);
    float* inv_rs = (float*)(ws + 35840);
    _Float16* Mt = (_Float16*)(ws + 68608);
    float* partials = (float*)(ws + 199680);

    hipMemsetAsync(ws + 32768, 0, 3072, stream);   // s + counters
    k1_norm<<<512, 256, 0, stream>>>(T, inv_norm, s);
    k2_all<<<1600, 256, 0, stream>>>(T, inv_norm, s, inv_rs, partials, Mt,
                                     out, counters);
}

// Round 13
// 96.993 us; speedup vs baseline: 8.0170x; 8.0170x over previous
//
#include <hip/hip_runtime.h>

#define N_ROWS 8192
#define DIM 256
#define EPSF 1e-8f

typedef _Float16 f16x8 __attribute__((ext_vector_type(8)));
typedef float f32x4 __attribute__((ext_vector_type(4)));

// ---------------------------------------------------------------------------
// D1: inv_norm (fp32) + fp64 column-sums of x_hat via LDS reduce + one
// f64 atomicAdd per thread (proven r1-r10).  512 blocks x 16 rows.
// ---------------------------------------------------------------------------
__global__ __launch_bounds__(256) void k1_norm(const float* __restrict__ T,
                                               float* __restrict__ inv_norm,
                                               double* __restrict__ s) {
    __shared__ double sacc[4][DIM];
    const int tid = threadIdx.x, bid = blockIdx.x;
    const int lane = tid & 63, wave = tid >> 6;
    double a0 = 0, a1 = 0, a2 = 0, a3 = 0;
#pragma unroll
    for (int r = 0; r < 4; ++r) {
        int row = bid * 16 + wave * 4 + r;
        float4 v = ((const float4*)(T + (size_t)row * DIM))[lane];
        float ss = v.x * v.x + v.y * v.y + v.z * v.z + v.w * v.w;
#pragma unroll
        for (int o = 32; o; o >>= 1) ss += __shfl_down(ss, o);
        ss = __shfl(ss, 0);
        float inv = 1.0f / fmaxf(sqrtf(ss), EPSF);
        if (lane == 0) inv_norm[row] = inv;
        a0 += (double)(v.x * inv);
        a1 += (double)(v.y * inv);
        a2 += (double)(v.z * inv);
        a3 += (double)(v.w * inv);
    }
    sacc[wave][lane * 4 + 0] = a0;
    sacc[wave][lane * 4 + 1] = a1;
    sacc[wave][lane * 4 + 2] = a2;
    sacc[wave][lane * 4 + 3] = a3;
    __syncthreads();
    double t = sacc[0][tid] + sacc[1][tid] + sacc[2][tid] + sacc[3][tid];
    atomicAdd(&s[tid], t);
}

// ---------------------------------------------------------------------------
// D2 (fused roles, NO cross-block sync — r11/r12 proved spin-chaining is
// 5-50x worse than dispatch boundaries on this chip):
//   blocks 0..1023    gemm: M-partials, fp16 MFMA, 64x64 tile, 128-row
//                     K-slab (split-K 64: r13 change — halves per-block
//                     barrier pipeline depth, doubles occupancy vs r10).
//   blocks 1024..3071 rs: inv_rs, ONE WAVE PER ROW (8192 indep waves).
// ---------------------------------------------------------------------------
__global__ __launch_bounds__(256) void k2_gemm_rs(const float* __restrict__ T,
                                                  const float* __restrict__ inv_norm,
                                                  const double* __restrict__ s,
                                                  float* __restrict__ inv_rs,
                                                  float* __restrict__ partials) {
    __shared__ _Float16 As[2][64][40];   // [buf][col][i]  10.2 KB
    __shared__ _Float16 Bs[2][64][40];   //                10.2 KB
    const int tid = threadIdx.x, bid = blockIdx.x;
    const int lane = tid & 63, wave = tid >> 6;

    if (bid >= 1024) {
        // ---- rs role: row = one wave.  fp64 dot (precision-critical:
        // rs ~6e-4 possible from cancellation; abs err budget ~1e-5).
        const int row = (bid - 1024) * 4 + wave;
        const double s0 = s[lane * 4 + 0];
        const double s1 = s[lane * 4 + 1];
        const double s2 = s[lane * 4 + 2];
        const double s3 = s[lane * 4 + 3];
        float4 v = ((const float4*)(T + (size_t)row * DIM))[lane];
        double d = (double)v.x * s0 + (double)v.y * s1 +
                   (double)v.z * s2 + (double)v.w * s3;
#pragma unroll
        for (int o = 32; o; o >>= 1) d += __shfl_down(d, o);
        if (lane == 0)
            inv_rs[row] = (float)(1.0 / (d * (double)inv_norm[row]));
        return;
    }

    // ---- gemm role: g in [0,1024): (kx,dy,z) = (4,4,64), 128-row slab
    const int g = bid;
    const int k0 = (g & 3) * 64;
    const int d0 = ((g >> 2) & 3) * 64;
    const int i0 = (g >> 4) * 128;
    const int wy = wave >> 1, wx = wave & 1;      // 2x2 waves -> 32x32 each
    const int lm = lane & 15, lg = lane >> 4;
    const int i = tid & 31, c8 = (tid >> 5) * 8;  // stage map: row i, 8 cols
    f32x4 acc[2][2] = {};
    float4 rA[2], rB[2];
    float rI;

    auto stage = [&](int ic) {
        int gi = i0 + ic + i;
        rI = inv_norm[gi];
        const float* rowp = T + (size_t)gi * DIM;
        rA[0] = *(const float4*)(rowp + k0 + c8);
        rA[1] = *(const float4*)(rowp + k0 + c8 + 4);
        rB[0] = *(const float4*)(rowp + d0 + c8);
        rB[1] = *(const float4*)(rowp + d0 + c8 + 4);
    };
    auto commit = [&](int buf) {
#pragma unroll
        for (int j = 0; j < 2; ++j) {
            float4 a = rA[j], b = rB[j];
            int c = c8 + j * 4;
            As[buf][c + 0][i] = (_Float16)(a.x * rI);
            As[buf][c + 1][i] = (_Float16)(a.y * rI);
            As[buf][c + 2][i] = (_Float16)(a.z * rI);
            As[buf][c + 3][i] = (_Float16)(a.w * rI);
            Bs[buf][c + 0][i] = (_Float16)b.x;
            Bs[buf][c + 1][i] = (_Float16)b.y;
            Bs[buf][c + 2][i] = (_Float16)b.z;
            Bs[buf][c + 3][i] = (_Float16)b.w;
        }
    };
    auto compute = [&](int buf) {
        f16x8 af[2], bf[2];
#pragma unroll
        for (int mt = 0; mt < 2; ++mt)
            af[mt] = *(const f16x8*)&As[buf][wy * 32 + mt * 16 + lm][lg * 8];
#pragma unroll
        for (int nt = 0; nt < 2; ++nt)
            bf[nt] = *(const f16x8*)&Bs[buf][wx * 32 + nt * 16 + lm][lg * 8];
#pragma unroll
        for (int mt = 0; mt < 2; ++mt)
#pragma unroll
            for (int nt = 0; nt < 2; ++nt)
                acc[mt][nt] = __builtin_amdgcn_mfma_f32_16x16x32_f16(
                    af[mt], bf[nt], acc[mt][nt], 0, 0, 0);
    };

    stage(0);
    commit(0);
    __syncthreads();
    for (int c = 1; c < 4; ++c) {
        stage(c * 32);            // global loads for chunk c in flight
        compute((c - 1) & 1);     // MFMA on previous chunk
        commit(c & 1);            // write other buffer (no reader conflict)
        __syncthreads();          // ONE barrier per chunk
    }
    compute(1);

    // C/D frag: col = lane&15, row = (lane>>4)*4 + reg (r5/r10-verified)
    float* pz = partials + (size_t)(g >> 4) * 65536;
#pragma unroll
    for (int mt = 0; mt < 2; ++mt) {
        int km = k0 + wy * 32 + mt * 16 + lg * 4;
#pragma unroll
        for (int nt = 0; nt < 2; ++nt) {
            int dn = d0 + wx * 32 + nt * 16 + lm;
#pragma unroll
            for (int r = 0; r < 4; ++r)
                pz[(size_t)(km + r) * 256 + dn] = acc[mt][nt][r];
        }
    }
}

// ---------------------------------------------------------------------------
// D3: reduce 64 partial slabs -> Mt (fp16, TRANSPOSED for k3's k-contiguous
// B loads).  16 MB of L3-hot reads, 128 KB writes.
// ---------------------------------------------------------------------------
__global__ __launch_bounds__(256) void k_reduceM(const float* __restrict__ partials,
                                                 _Float16* __restrict__ Mt) {
    const int gidx = blockIdx.x * 256 + threadIdx.x;
    const int k = gidx >> 8, d = gidx & 255;
    const float* p = partials + (size_t)k * 256 + d;
    float a0 = 0.f, a1 = 0.f, a2 = 0.f, a3 = 0.f;
#pragma unroll
    for (int z = 0; z < 64; z += 4) {
        a0 += p[(size_t)(z + 0) * 65536];
        a1 += p[(size_t)(z + 1) * 65536];
        a2 += p[(size_t)(z + 2) * 65536];
        a3 += p[(size_t)(z + 3) * 65536];
    }
    Mt[(size_t)d * 256 + k] = (_Float16)((a0 + a1) + (a2 + a3));
}

// ---------------------------------------------------------------------------
// D4: out = diag(inv_rs) * Xhat * M via fp16 MFMA.  32x64 tiles -> 1024
// blocks (4 blocks/CU), double-buffered LDS, one barrier per chunk.
// ---------------------------------------------------------------------------
__global__ __launch_bounds__(256) void k3_mfma(const float* __restrict__ T,
                                               const float* __restrict__ inv_norm,
                                               const _Float16* __restrict__ Mt,
                                               const float* __restrict__ inv_rs,
                                               float* __restrict__ out) {
    __shared__ _Float16 As[2][32][40];   // [buf][i][k]   5.1 KB
    __shared__ _Float16 Bs[2][64][40];   // [buf][d][k]  10.2 KB
    const int tid = threadIdx.x, bid = blockIdx.x;
    const int lane = tid & 63, wave = tid >> 6;
    const int i0 = (bid >> 2) * 32;
    const int d0 = (bid & 3) * 64;
    const int wy = wave >> 1, wx = wave & 1;     // wave tile 16 x 32
    const int lm = lane & 15, lg = lane >> 4;
    f32x4 acc[2] = {};
    float4 rA;
    float rI;
    f16x8 rB;
    const int ia = tid >> 3, c4 = (tid & 7) * 4;   // A: row ia, 4 k-cols
    const int db = tid >> 2, k8 = (tid & 3) * 8;   // B: row db, 8 k-cols

    auto stage = [&](int kc) {
        rI = inv_norm[i0 + ia];
        rA = *(const float4*)(T + (size_t)(i0 + ia) * DIM + kc + c4);
        rB = *(const f16x8*)(Mt + (size_t)(d0 + db) * 256 + kc + k8);
    };
    auto commit = [&](int buf) {
        As[buf][ia][c4 + 0] = (_Float16)(rA.x * rI);
        As[buf][ia][c4 + 1] = (_Float16)(rA.y * rI);
        As[buf][ia][c4 + 2] = (_Float16)(rA.z * rI);
        As[buf][ia][c4 + 3] = (_Float16)(rA.w * rI);
        *(f16x8*)&Bs[buf][db][k8] = rB;
    };
    auto compute = [&](int buf) {
        f16x8 af = *(const f16x8*)&As[buf][wy * 16 + lm][lg * 8];
        f16x8 bf0 = *(const f16x8*)&Bs[buf][wx * 32 + lm][lg * 8];
        f16x8 bf1 = *(const f16x8*)&Bs[buf][wx * 32 + 16 + lm][lg * 8];
        acc[0] = __builtin_amdgcn_mfma_f32_16x16x32_f16(af, bf0, acc[0], 0, 0, 0);
        acc[1] = __builtin_amdgcn_mfma_f32_16x16x32_f16(af, bf1, acc[1], 0, 0, 0);
    };

    stage(0);
    commit(0);
    __syncthreads();
    for (int c = 1; c < 8; ++c) {
        stage(c * 32);
        compute((c - 1) & 1);
        commit(c & 1);
        __syncthreads();
    }
    compute(1);

#pragma unroll
    for (int r = 0; r < 4; ++r) {
        int gi = i0 + wy * 16 + lg * 4 + r;
        float ir = inv_rs[gi];
        out[(size_t)gi * DIM + d0 + wx * 32 + lm] = acc[0][r] * ir;
        out[(size_t)gi * DIM + d0 + wx * 32 + 16 + lm] = acc[1][r] * ir;
    }
}

// ---------------------------------------------------------------------------
extern "C" void kernel_launch(void* const* d_in, const int* in_sizes, int n_in,
                              void* d_out, int out_size, void* d_ws, size_t ws_size,
                              hipStream_t stream) {
    const float* T = (const float*)d_in[0];
    float* out = (float*)d_out;

    // workspace layout (16B-aligned, ~16.6 MB of 256 MiB):
    //   [0,       32768)   inv_norm  float[8192]
    //   [32768,   34816)   s         double[256]
    //   [34816,   67584)   inv_rs    float[8192]
    //   [67584,   198656)  Mt        _Float16[256][256]  (M transposed)
    //   [198656,  +16 MiB) partials  float[64][256][256]
    char* ws = (char*)d_ws;
    float* inv_norm = (float*)(ws);
    double* s = (double*)(ws + 32768);
    float* inv_rs = (float*)(ws + 34816);
    _Float16* Mt = (_Float16*)(ws + 67584);
    float* partials = (float*)(ws + 198656);

    hipMemsetAsync(s, 0, 256 * sizeof(double), stream);
    k1_norm<<<512, 256, 0, stream>>>(T, inv_norm, s);
    k2_gemm_rs<<<3072, 256, 0, stream>>>(T, inv_norm, s, inv_rs, partials);
    k_reduceM<<<256, 256, 0, stream>>>(partials, Mt);
    k3_mfma<<<1024, 256, 0, stream>>>(T, inv_norm, Mt, inv_rs, out);
}